// Round 14
// baseline (1724.559 us; speedup 1.0000x reference)
//
#include <hip/hip_runtime.h>

#define NNODE 100000
#define NEDGE 800000
#define EB 256
// H = 4, D = 32, H*D = 128, DN = DE = 32, NL = 3

typedef __attribute__((ext_vector_type(8))) short short8;   // 8 bf16 (4 VGPRs)
typedef __attribute__((ext_vector_type(4))) float f32x4;

__device__ __forceinline__ short bf16_rne(float f) {
    unsigned u = __float_as_uint(f);
    unsigned r = u + 0x7FFFu + ((u >> 16) & 1u);
    return (short)(r >> 16);
}
__device__ __forceinline__ float bf16_to_f32(short s) {
    return __uint_as_float(((unsigned)(unsigned short)s) << 16);
}
__device__ __forceinline__ void split8(float4 a, float4 b, short8& hi, short8& lo) {
    float v[8] = {a.x, a.y, a.z, a.w, b.x, b.y, b.z, b.w};
    #pragma unroll
    for (int i = 0; i < 8; i++) {
        short h = bf16_rne(v[i]);
        hi[i] = h;
        lo[i] = bf16_rne(v[i] - bf16_to_f32(h));
    }
}

// ---------------------------------------------------------------------------
// CSR build kernels (dst-indexed), run once per call
// ---------------------------------------------------------------------------
__global__ __launch_bounds__(256) void zero_ints(int* __restrict__ a, int* __restrict__ b, int n) {
    int i = blockIdx.x * 256 + threadIdx.x;
    if (i < n) { a[i] = 0; b[i] = 0; }
}

__global__ __launch_bounds__(256) void count_dst(const int* __restrict__ dst, int* __restrict__ counts) {
    int e = blockIdx.x * 256 + threadIdx.x;
    if (e < NEDGE) atomicAdd(&counts[dst[e]], 1);
}

__global__ __launch_bounds__(256) void scan_chunks(const int* __restrict__ counts, int* __restrict__ ro,
                                                   int* __restrict__ bsums, int n) {
    __shared__ int sh[256];
    int base = blockIdx.x * 1024;
    int t = threadIdx.x;
    int v[4];
    int s = 0;
    #pragma unroll
    for (int i = 0; i < 4; i++) {
        int idx = base + t * 4 + i;
        int c = (idx < n) ? counts[idx] : 0;
        v[i] = s; s += c;
    }
    sh[t] = s; __syncthreads();
    for (int off = 1; off < 256; off <<= 1) {
        int x = 0;
        if (t >= off) x = sh[t - off];
        __syncthreads();
        if (t >= off) sh[t] += x;
        __syncthreads();
    }
    int thr_excl = (t > 0) ? sh[t - 1] : 0;
    #pragma unroll
    for (int i = 0; i < 4; i++) {
        int idx = base + t * 4 + i;
        if (idx < n) ro[idx] = thr_excl + v[i];
    }
    if (t == 255) bsums[blockIdx.x] = sh[255];
}

__global__ __launch_bounds__(256) void scan_bsums(int* __restrict__ bsums, int nb) {
    __shared__ int sh[256];
    int t = threadIdx.x;
    int val = (t < nb) ? bsums[t] : 0;
    sh[t] = val; __syncthreads();
    for (int off = 1; off < 256; off <<= 1) {
        int x = 0;
        if (t >= off) x = sh[t - off];
        __syncthreads();
        if (t >= off) sh[t] += x;
        __syncthreads();
    }
    int excl = (t > 0) ? sh[t - 1] : 0;
    if (t < nb) bsums[t] = excl;
}

__global__ __launch_bounds__(256) void scan_add(int* __restrict__ ro, const int* __restrict__ bsums, int n) {
    int i = blockIdx.x * 256 + threadIdx.x;
    if (i < n) ro[i] += bsums[i >> 10];
    if (i == 0) ro[n] = NEDGE;
}

__global__ __launch_bounds__(256) void scatter_edges(const int* __restrict__ src, const int* __restrict__ dst,
                                                     const int* __restrict__ ro, int* __restrict__ cursor,
                                                     int* __restrict__ eidx, int* __restrict__ src_p,
                                                     int* __restrict__ dst_p) {
    int e = blockIdx.x * 256 + threadIdx.x;
    if (e < NEDGE) {
        int d = dst[e];
        int pos = atomicAdd(&cursor[d], 1);
        int idx = ro[d] + pos;
        eidx[idx] = e;
        src_p[idx] = src[e];
        dst_p[idx] = d;
    }
}

// ---------------------------------------------------------------------------
// W prep: per layer build W'[k 0:128][j 0:128] bf16, k<64 = hi of [Wfij;Wni],
// k>=64 = lo. Stored TRANSPOSED as granules: granule (j, g) = 8 bf16 of
// W'[g*8..g*8+7][j], placed at slot j*16 + (g ^ (j&15))  (XOR swizzle).
// ---------------------------------------------------------------------------
__global__ __launch_bounds__(256) void wprep(
    const float* __restrict__ Wfij, const float* __restrict__ Wni,
    short* __restrict__ Wp) {
    int gid = blockIdx.x * 256 + threadIdx.x;     // 0..6143
    int l = gid >> 11;
    int r = gid & 2047;
    int j = r >> 4, g = r & 15;
    const float* Wf = Wfij + l * 4096;
    const float* Wn = Wni + l * 4096;
    short8 out;
    #pragma unroll
    for (int i = 0; i < 8; i++) {
        int k = (g & 7) * 8 + i;
        float wv = (k < 32) ? Wf[k * 128 + j] : Wn[(k - 32) * 128 + j];
        short h = bf16_rne(wv);
        if (g >= 8) {
            float lo = wv - bf16_to_f32(h);
            out[i] = bf16_rne(lo);
        } else {
            out[i] = h;
        }
    }
    ((short8*)Wp)[(size_t)l * 2048 + j * 16 + (g ^ (j & 15))] = out;
}

// ---------------------------------------------------------------------------
// MFMA edge kernel, 512 threads / 8 waves / 256 edges per block.
// C[e][j] = bias[j] + sum_k A[e][k] W[k][j], A = [ef | nf[src]] via
// split-bf16 (ah*wh + al*wh + ah*wl). Wave w owns edges w*32..w*32+31.
// Epilogue: 4 quarters of 64 edges restaged through a shared 64x140 LDS
// buffer; 8 threads/edge consume (h = (t&7)>>1, half-row of 16 cols);
// outputs staged and written with block-linear copies.
// LDS: sBuf 35840 B + sLg 4096 B = 39.9 KB -> 4 blocks/CU = 32 waves/CU.
// ---------------------------------------------------------------------------
template <bool WRITE_EF, bool GATHER_EF>
__global__ __launch_bounds__(512, 8) void edge_mfma(
    const float* __restrict__ ef_in,     // E x 32
    const int* __restrict__ eidx,        // permuted -> orig (GATHER_EF only)
    const int* __restrict__ src_p, const int* __restrict__ dst_p,
    const float* __restrict__ nf_cur,    // N x 32
    const float* __restrict__ f_nj,      // N x 128
    const short* __restrict__ Wp,        // layer slice: 2048 pre-swizzled granules
    const float* __restrict__ attn,      // 4x32 layer slice
    const float* __restrict__ bias,      // 128 layer slice
    float* __restrict__ logits,          // E x 4 (permuted order)
    float* __restrict__ ef_out) {        // E x 32 (permuted order)
    __shared__ float sBuf[8960];         // W' (8192 floats) / C-restage 64x140
    __shared__ float sLg[1024];          // logits staging for 256 edges

    int t = threadIdx.x;
    int lane = t & 63;
    int w = t >> 6;                      // wave 0..7
    int m16 = lane & 15, ks = lane >> 4;
    int e0b = blockIdx.x * EB;

    // ---- stage W' (coalesced, already swizzled) ----
    {
        const float4* wp4 = (const float4*)Wp;
        float4* sw4 = (float4*)sBuf;
        #pragma unroll
        for (int i = 0; i < 4; i++) sw4[t + i * 512] = wp4[t + i * 512];
    }

    // ---- build A fragments from global (no LDS) ----
    short8 aefh[2], aefl[2], anfh[2], anfl[2];
    int eb = e0b + w * 32;
    #pragma unroll
    for (int mt = 0; mt < 2; mt++) {
        int ep = eb + mt * 16 + m16;
        long er = GATHER_EF ? (long)eidx[ep] : (long)ep;
        const float* efp = ef_in + (size_t)er * 32 + ks * 8;
        float4 a0 = *(const float4*)efp;
        float4 a1 = *(const float4*)(efp + 4);
        int sr = src_p[ep];
        const float* nfp = nf_cur + (size_t)sr * 32 + ks * 8;
        float4 b0 = *(const float4*)nfp;
        float4 b1 = *(const float4*)(nfp + 4);
        split8(a0, a1, aefh[mt], aefl[mt]);
        split8(b0, b1, anfh[mt], anfl[mt]);
    }
    __syncthreads();

    // ---- acc init = bias[j] (uniform down columns) ----
    f32x4 acc[2][8];
    #pragma unroll
    for (int jt = 0; jt < 8; jt++) {
        float bv = bias[jt * 16 + m16];
        #pragma unroll
        for (int mt = 0; mt < 2; mt++) {
            f32x4 c = {bv, bv, bv, bv};
            acc[mt][jt] = c;
        }
    }

    // ---- MFMA main loop ----
    const short8* sw8 = (const short8*)sBuf;
    #pragma unroll
    for (int jt = 0; jt < 8; jt++) {
        int jrow = (jt * 16 + m16) * 16;
        short8 bh0 = sw8[jrow + ((0 + ks) ^ m16)];    // wh, k 0:32  (ef)
        short8 bh1 = sw8[jrow + ((4 + ks) ^ m16)];    // wh, k 32:64 (nf)
        short8 bl0 = sw8[jrow + ((8 + ks) ^ m16)];    // wl, k 0:32
        short8 bl1 = sw8[jrow + ((12 + ks) ^ m16)];   // wl, k 32:64
        #pragma unroll
        for (int mt = 0; mt < 2; mt++) {
            f32x4 c = acc[mt][jt];
            c = __builtin_amdgcn_mfma_f32_16x16x32_bf16(aefh[mt], bh0, c, 0, 0, 0);
            c = __builtin_amdgcn_mfma_f32_16x16x32_bf16(anfh[mt], bh1, c, 0, 0, 0);
            c = __builtin_amdgcn_mfma_f32_16x16x32_bf16(aefl[mt], bh0, c, 0, 0, 0);
            c = __builtin_amdgcn_mfma_f32_16x16x32_bf16(anfl[mt], bh1, c, 0, 0, 0);
            c = __builtin_amdgcn_mfma_f32_16x16x32_bf16(aefh[mt], bl0, c, 0, 0, 0);
            c = __builtin_amdgcn_mfma_f32_16x16x32_bf16(anfh[mt], bl1, c, 0, 0, 0);
            acc[mt][jt] = c;
        }
    }

    // ---- epilogue in 4 quarters of 64 edges (C restage via LDS) ----
    int sub = t & 7;              // 8 threads per edge
    int h = sub >> 1;             // head 0..3
    int half = sub & 1;           // 16-col half of the head
    int e_l = t >> 3;             // edge 0..63 within quarter
    for (int q = 0; q < 4; q++) {
        __syncthreads();   // W'/previous-quarter reads complete
        if ((w >> 1) == q) {
            int eoff = (w & 1) * 32 + ks * 4;
            #pragma unroll
            for (int mt = 0; mt < 2; mt++)
                #pragma unroll
                for (int jt = 0; jt < 8; jt++) {
                    int colp = (jt >> 1) * 36 + (jt & 1) * 16 + m16;
                    f32x4 c = acc[mt][jt];
                    #pragma unroll
                    for (int r = 0; r < 4; r++)
                        sBuf[(eoff + mt * 16 + r) * 140 + colp] = c[r];
                }
        }
        __syncthreads();
        int ep = e0b + q * 64 + e_l;
        const float* cr = sBuf + e_l * 140 + h * 36 + half * 16;
        int dn = dst_p[ep];
        const float* fr = f_nj + (size_t)dn * 128 + h * 32 + half * 16;
        const float* ar = attn + h * 32 + half * 16;
        float x[16];
        float lg = 0.f;
        #pragma unroll
        for (int qq = 0; qq < 4; qq++) {
            float4 cv = *(const float4*)(cr + qq * 4);
            float4 fv = *(const float4*)(fr + qq * 4);
            float4 av = *(const float4*)(ar + qq * 4);
            float v0 = cv.x + fv.x; v0 = (v0 >= 0.f) ? v0 : 0.2f * v0; lg = fmaf(v0, av.x, lg);
            float v1 = cv.y + fv.y; v1 = (v1 >= 0.f) ? v1 : 0.2f * v1; lg = fmaf(v1, av.y, lg);
            float v2 = cv.z + fv.z; v2 = (v2 >= 0.f) ? v2 : 0.2f * v2; lg = fmaf(v2, av.z, lg);
            float v3 = cv.w + fv.w; v3 = (v3 >= 0.f) ? v3 : 0.2f * v3; lg = fmaf(v3, av.w, lg);
            x[qq * 4 + 0] = v0; x[qq * 4 + 1] = v1; x[qq * 4 + 2] = v2; x[qq * 4 + 3] = v3;
        }
        lg += __shfl_xor(lg, 1);            // combine the two halves of this head
        if (half == 0) sLg[(q * 64 + e_l) * 4 + h] = lg;
        if (WRITE_EF) {
            #pragma unroll
            for (int i = 0; i < 16; i++) {
                x[i] += __shfl_xor(x[i], 2);    // h ^ 1
                x[i] += __shfl_xor(x[i], 4);    // h ^ 2
            }
            if (h == 0) {
                // overwrite this edge's own (consumed) C columns half*16..+15
                float* mp = sBuf + e_l * 140 + half * 16;
                #pragma unroll
                for (int qq = 0; qq < 4; qq++)
                    *(float4*)(mp + qq * 4) = make_float4(x[qq*4] * 0.25f, x[qq*4+1] * 0.25f,
                                                          x[qq*4+2] * 0.25f, x[qq*4+3] * 0.25f);
            }
        }
        __syncthreads();
        if (WRITE_EF) {
            // block-linear copy: 64 rows x 32 floats -> efA contiguous (512 float4)
            float4* eo = (float4*)(ef_out + (size_t)(e0b + q * 64) * 32);
            int row = t >> 3, qq = t & 7;
            eo[t] = *(const float4*)(sBuf + row * 140 + qq * 4);
        }
    }
    __syncthreads();
    if (t < 256)
        ((float4*)(logits + (size_t)e0b * 4))[t] = ((const float4*)sLg)[t];
}

// ---------------------------------------------------------------------------
// One wave per dst node; single pass (softmax is shift-invariant; logits are
// O(10) so raw exp is safe in fp32).
__global__ __launch_bounds__(256) void aggregate(
    const int* __restrict__ ro, const int* __restrict__ src_p,
    const float* __restrict__ logits,  // E x 4 (permuted)
    const float* __restrict__ nf_cur,  // N x 32
    float* __restrict__ agg) {         // N x 128
    int wid = (blockIdx.x * 256 + threadIdx.x) >> 6;
    int lane = threadIdx.x & 63;
    if (wid >= NNODE) return;
    int beg = ro[wid], end = ro[wid + 1];
    float* arow = agg + (size_t)wid * 128;
    if (beg == end) {
        arow[lane] = 0.f;
        arow[lane + 64] = 0.f;
        return;
    }
    int hA = lane >> 5;
    int k = lane & 31;
    float den1 = 0.f, den2 = 0.f, acc1 = 0.f, acc2 = 0.f;
    for (int i = beg; i < end; i++) {
        int s = src_p[i];
        float a1 = __expf(logits[(size_t)i * 4 + hA]);
        float a2 = __expf(logits[(size_t)i * 4 + hA + 2]);
        den1 += a1; den2 += a2;
        float v = nf_cur[(size_t)s * 32 + k];
        acc1 = fmaf(a1, v, acc1);
        acc2 = fmaf(a2, v, acc2);
    }
    arow[lane] = acc1 / den1;
    arow[lane + 64] = acc2 / den2;
}

// ---------------------------------------------------------------------------
// Tiled node-post GEMM (unchanged): 128-node tile, 256 thr, grid 782.
// ---------------------------------------------------------------------------
template <bool AGG, bool WRITE_FNJ>
__global__ __launch_bounds__(256, 3) void post_gemm(
    const float* __restrict__ Xin,
    const float* __restrict__ Wnode,
    const float* __restrict__ Wnj_n,
    float* __restrict__ nf_next,
    float* __restrict__ fnj_next) {
    __shared__ float sW1[128 * 34];
    __shared__ float sA[32 * 129];
    __shared__ float sW2[32 * 132];
    int t = threadIdx.x;
    int gn0 = blockIdx.x * 128;

    if (AGG) {
        const float4* wsrc = (const float4*)Wnode;
        #pragma unroll
        for (int i = 0; i < 4; i++) {
            int f = t + i * 256;
            int k = f >> 3, dq = f & 7;
            *(float4*)(sW1 + k * 34 + dq * 4) = wsrc[(k & 31) * 32 + (k >> 5) * 8 + dq];
        }
    }
    if (WRITE_FNJ) {
        const float4* wsrc = (const float4*)Wnj_n;
        #pragma unroll
        for (int i = 0; i < 4; i++) {
            int f = t + i * 256;
            int d = f >> 5, jq = f & 31;
            *(float4*)(sW2 + d * 132 + jq * 4) = wsrc[f];
        }
    }

    int nrow = t & 127;
    int half = t >> 7;
    bool rvalid = (gn0 + nrow) < NNODE;

    float c1[8][2];
    int cg = t & 15, ng = t >> 4;
    int c0 = cg * 2, n0 = ng * 8;

    if (AGG) {
        #pragma unroll
        for (int i = 0; i < 8; i++) { c1[i][0] = 0.f; c1[i][1] = 0.f; }
        const float4* arow = (const float4*)(Xin + (size_t)(gn0 + nrow) * 128);
        for (int ch = 0; ch < 4; ch++) {
            __syncthreads();
            #pragma unroll
            for (int q = 0; q < 4; q++) {
                float4 v = rvalid ? arow[ch * 8 + half * 4 + q]
                                  : make_float4(0.f, 0.f, 0.f, 0.f);
                int kk = half * 16 + q * 4;
                sA[(kk + 0) * 129 + nrow] = v.x;
                sA[(kk + 1) * 129 + nrow] = v.y;
                sA[(kk + 2) * 129 + nrow] = v.z;
                sA[(kk + 3) * 129 + nrow] = v.w;
            }
            __syncthreads();
            #pragma unroll 4
            for (int k = 0; k < 32; k++) {
                float4 a0 = *(const float4*)(sA + k * 129 + n0);
                float4 a1 = *(const float4*)(sA + k * 129 + n0 + 4);
                float2 wv = *(const float2*)(sW1 + (ch * 32 + k) * 34 + c0);
                float av[8] = {a0.x, a0.y, a0.z, a0.w, a1.x, a1.y, a1.z, a1.w};
                #pragma unroll
                for (int i = 0; i < 8; i++) {
                    c1[i][0] = fmaf(av[i], wv.x, c1[i][0]);
                    c1[i][1] = fmaf(av[i], wv.y, c1[i][1]);
                }
            }
        }
        #pragma unroll
        for (int i = 0; i < 8; i++) { c1[i][0] *= 0.25f; c1[i][1] *= 0.25f; }
        #pragma unroll
        for (int i = 0; i < 8; i++) {
            int n = gn0 + n0 + i;
            if (n < NNODE)
                *(float2*)(nf_next + (size_t)n * 32 + c0) = make_float2(c1[i][0], c1[i][1]);
        }
    }

    if (WRITE_FNJ) {
        __syncthreads();
        if (AGG) {
            #pragma unroll
            for (int i = 0; i < 8; i++) {
                sA[(c0 + 0) * 129 + n0 + i] = c1[i][0];
                sA[(c0 + 1) * 129 + n0 + i] = c1[i][1];
            }
        } else {
            const float4* xr = (const float4*)(Xin + (size_t)(gn0 + nrow) * 32);
            #pragma unroll
            for (int q = 0; q < 4; q++) {
                float4 v = rvalid ? xr[half * 4 + q] : make_float4(0.f, 0.f, 0.f, 0.f);
                int dd = half * 16 + q * 4;
                sA[(dd + 0) * 129 + nrow] = v.x;
                sA[(dd + 1) * 129 + nrow] = v.y;
                sA[(dd + 2) * 129 + nrow] = v.z;
                sA[(dd + 3) * 129 + nrow] = v.w;
            }
        }
        __syncthreads();

        int jg = t & 15, ng2 = t >> 4;
        int j0 = jg * 8, m0 = ng2 * 8;
        float f[8][8];
        #pragma unroll
        for (int i = 0; i < 8; i++)
            #pragma unroll
            for (int j = 0; j < 8; j++) f[i][j] = 0.f;
        #pragma unroll 4
        for (int d = 0; d < 32; d++) {
            float4 a0 = *(const float4*)(sA + d * 129 + m0);
            float4 a1 = *(const float4*)(sA + d * 129 + m0 + 4);
            float4 w0 = *(const float4*)(sW2 + d * 132 + j0);
            float4 w1 = *(const float4*)(sW2 + d * 132 + j0 + 4);
            float av[8] = {a0.x, a0.y, a0.z, a0.w, a1.x, a1.y, a1.z, a1.w};
            float wv[8] = {w0.x, w0.y, w0.z, w0.w, w1.x, w1.y, w1.z, w1.w};
            #pragma unroll
            for (int i = 0; i < 8; i++)
                #pragma unroll
                for (int j = 0; j < 8; j++)
                    f[i][j] = fmaf(av[i], wv[j], f[i][j]);
        }
        #pragma unroll
        for (int i = 0; i < 8; i++) {
            int n = gn0 + m0 + i;
            if (n < NNODE) {
                float* fo = fnj_next + (size_t)n * 128 + j0;
                *(float4*)(fo) = make_float4(f[i][0], f[i][1], f[i][2], f[i][3]);
                *(float4*)(fo + 4) = make_float4(f[i][4], f[i][5], f[i][6], f[i][7]);
            }
        }
    }
}

// ---------------------------------------------------------------------------
extern "C" void kernel_launch(void* const* d_in, const int* in_sizes, int n_in,
                              void* d_out, int out_size, void* d_ws, size_t ws_size,
                              hipStream_t stream) {
    const float* nf   = (const float*)d_in[0];
    const float* ef   = (const float*)d_in[1];
    const int*   src  = (const int*)d_in[2];
    const int*   dst  = (const int*)d_in[3];
    const float* Wni  = (const float*)d_in[4];
    const float* Wnj  = (const float*)d_in[5];
    const float* Wfij = (const float*)d_in[6];
    const float* Wnd  = (const float*)d_in[7];
    const float* attn = (const float*)d_in[8];
    const float* bias = (const float*)d_in[9];
    float* out = (float*)d_out;

    char* ws = (char*)d_ws;
    size_t off = 0;
    auto alloc = [&](size_t bytes) {
        void* p = ws + off;
        off += (bytes + 255) & ~(size_t)255;
        return p;
    };
    float* fnj    = (float*)alloc((size_t)NNODE * 128 * 4);
    float* agg    = (float*)alloc((size_t)(NNODE + 128) * 128 * 4);
    float* efA    = (float*)alloc((size_t)NEDGE * 32 * 4);
    float* logits = (float*)alloc((size_t)NEDGE * 4 * 4);
    float* nfA    = (float*)alloc((size_t)NNODE * 32 * 4);
    float* nfB    = (float*)alloc((size_t)NNODE * 32 * 4);
    short* Wp     = (short*)alloc((size_t)3 * 2048 * 16);   // split/transposed/swizzled W
    int*   counts = (int*)alloc((size_t)NNODE * 4);
    int*   cursor = (int*)alloc((size_t)NNODE * 4);
    int*   ro     = (int*)alloc((size_t)(NNODE + 1) * 4);
    int*   eidx   = (int*)alloc((size_t)NEDGE * 4);
    int*   src_p  = (int*)alloc((size_t)NEDGE * 4);
    int*   dst_p  = (int*)alloc((size_t)NEDGE * 4);
    int*   bsums  = (int*)alloc(1024 * 4);

    const int NB_E = (NEDGE + 255) / 256;          // 3125
    const int NB_N = (NNODE + 255) / 256;          // 391
    const int NB_AGG = (NNODE + 3) / 4;            // 25000
    const int NB_SCAN = (NNODE + 1023) / 1024;     // 98
    const int NB_ET = NEDGE / EB;                  // 3125
    const int NB_PG = (NNODE + 127) / 128;         // 782

    zero_ints<<<NB_N, 256, 0, stream>>>(counts, cursor, NNODE);
    count_dst<<<NB_E, 256, 0, stream>>>(dst, counts);
    scan_chunks<<<NB_SCAN, 256, 0, stream>>>(counts, ro, bsums, NNODE);
    scan_bsums<<<1, 256, 0, stream>>>(bsums, NB_SCAN);
    scan_add<<<NB_N, 256, 0, stream>>>(ro, bsums, NNODE);
    scatter_edges<<<NB_E, 256, 0, stream>>>(src, dst, ro, cursor, eidx, src_p, dst_p);
    wprep<<<24, 256, 0, stream>>>(Wfij, Wni, Wp);

    // layer-0 f_nj = nf @ Wnj[0]  (DIRECT path: GEMM2 only)
    post_gemm<false, true><<<NB_PG, 256, 0, stream>>>(nf, nullptr, Wnj, nullptr, fnj);

    // ----- layer 0 -----
    edge_mfma<true, true><<<NB_ET, 512, 0, stream>>>(ef, eidx, src_p, dst_p, nf, fnj,
                                                     Wp, attn, bias, logits, efA);
    aggregate<<<NB_AGG, 256, 0, stream>>>(ro, src_p, logits, nf, agg);
    post_gemm<true, true><<<NB_PG, 256, 0, stream>>>(agg, Wnd, Wnj + 4096, nfA, fnj);

    // ----- layer 1 -----
    edge_mfma<true, false><<<NB_ET, 512, 0, stream>>>(efA, nullptr, src_p, dst_p, nfA, fnj,
                                                      Wp + 16384, attn + 128, bias + 128,
                                                      logits, efA);
    aggregate<<<NB_AGG, 256, 0, stream>>>(ro, src_p, logits, nfA, agg);
    post_gemm<true, true><<<NB_PG, 256, 0, stream>>>(agg, Wnd + 4096, Wnj + 8192, nfB, fnj);

    // ----- layer 2 -----
    edge_mfma<false, false><<<NB_ET, 512, 0, stream>>>(efA, nullptr, src_p, dst_p, nfB, fnj,
                                                       Wp + 32768, attn + 256, bias + 256,
                                                       logits, nullptr);
    aggregate<<<NB_AGG, 256, 0, stream>>>(ro, src_p, logits, nfB, agg);
    post_gemm<true, false><<<NB_PG, 256, 0, stream>>>(agg, Wnd + 8192, nullptr, out, nullptr);
}

// Round 15
// 878.160 us; speedup vs baseline: 1.9638x; 1.9638x over previous
//
#include <hip/hip_runtime.h>

#define NNODE 100000
#define NEDGE 800000
#define EB 128
// H = 4, D = 32, H*D = 128, DN = DE = 32, NL = 3

typedef __attribute__((ext_vector_type(8))) short short8;   // 8 bf16 (4 VGPRs)
typedef __attribute__((ext_vector_type(4))) float f32x4;

__device__ __forceinline__ short bf16_rne(float f) {
    unsigned u = __float_as_uint(f);
    unsigned r = u + 0x7FFFu + ((u >> 16) & 1u);
    return (short)(r >> 16);
}
__device__ __forceinline__ float bf16_to_f32(short s) {
    return __uint_as_float(((unsigned)(unsigned short)s) << 16);
}
__device__ __forceinline__ void split8(float4 a, float4 b, short8& hi, short8& lo) {
    float v[8] = {a.x, a.y, a.z, a.w, b.x, b.y, b.z, b.w};
    #pragma unroll
    for (int i = 0; i < 8; i++) {
        short h = bf16_rne(v[i]);
        hi[i] = h;
        lo[i] = bf16_rne(v[i] - bf16_to_f32(h));
    }
}

// ---------------------------------------------------------------------------
// CSR build kernels (dst-indexed), run once per call
// ---------------------------------------------------------------------------
__global__ __launch_bounds__(256) void zero_ints(int* __restrict__ a, int* __restrict__ b, int n) {
    int i = blockIdx.x * 256 + threadIdx.x;
    if (i < n) { a[i] = 0; b[i] = 0; }
}

__global__ __launch_bounds__(256) void count_dst(const int* __restrict__ dst, int* __restrict__ counts) {
    int e = blockIdx.x * 256 + threadIdx.x;
    if (e < NEDGE) atomicAdd(&counts[dst[e]], 1);
}

__global__ __launch_bounds__(256) void scan_chunks(const int* __restrict__ counts, int* __restrict__ ro,
                                                   int* __restrict__ bsums, int n) {
    __shared__ int sh[256];
    int base = blockIdx.x * 1024;
    int t = threadIdx.x;
    int v[4];
    int s = 0;
    #pragma unroll
    for (int i = 0; i < 4; i++) {
        int idx = base + t * 4 + i;
        int c = (idx < n) ? counts[idx] : 0;
        v[i] = s; s += c;
    }
    sh[t] = s; __syncthreads();
    for (int off = 1; off < 256; off <<= 1) {
        int x = 0;
        if (t >= off) x = sh[t - off];
        __syncthreads();
        if (t >= off) sh[t] += x;
        __syncthreads();
    }
    int thr_excl = (t > 0) ? sh[t - 1] : 0;
    #pragma unroll
    for (int i = 0; i < 4; i++) {
        int idx = base + t * 4 + i;
        if (idx < n) ro[idx] = thr_excl + v[i];
    }
    if (t == 255) bsums[blockIdx.x] = sh[255];
}

__global__ __launch_bounds__(256) void scan_bsums(int* __restrict__ bsums, int nb) {
    __shared__ int sh[256];
    int t = threadIdx.x;
    int val = (t < nb) ? bsums[t] : 0;
    sh[t] = val; __syncthreads();
    for (int off = 1; off < 256; off <<= 1) {
        int x = 0;
        if (t >= off) x = sh[t - off];
        __syncthreads();
        if (t >= off) sh[t] += x;
        __syncthreads();
    }
    int excl = (t > 0) ? sh[t - 1] : 0;
    if (t < nb) bsums[t] = excl;
}

__global__ __launch_bounds__(256) void scan_add(int* __restrict__ ro, const int* __restrict__ bsums, int n) {
    int i = blockIdx.x * 256 + threadIdx.x;
    if (i < n) ro[i] += bsums[i >> 10];
    if (i == 0) ro[n] = NEDGE;
}

__global__ __launch_bounds__(256) void scatter_edges(const int* __restrict__ src, const int* __restrict__ dst,
                                                     const int* __restrict__ ro, int* __restrict__ cursor,
                                                     int* __restrict__ eidx, int* __restrict__ src_p,
                                                     int* __restrict__ dst_p) {
    int e = blockIdx.x * 256 + threadIdx.x;
    if (e < NEDGE) {
        int d = dst[e];
        int pos = atomicAdd(&cursor[d], 1);
        int idx = ro[d] + pos;
        eidx[idx] = e;
        src_p[idx] = src[e];
        dst_p[idx] = d;
    }
}

// ---------------------------------------------------------------------------
// W prep: per layer build W'[k 0:128][j 0:128] bf16, k<64 = hi of [Wfij;Wni],
// k>=64 = lo. Stored TRANSPOSED as granules: granule (j, g) = 8 bf16 of
// W'[g*8..g*8+7][j], placed at slot j*16 + (g ^ (j&15))  (XOR swizzle).
// ---------------------------------------------------------------------------
__global__ __launch_bounds__(256) void wprep(
    const float* __restrict__ Wfij, const float* __restrict__ Wni,
    short* __restrict__ Wp) {
    int gid = blockIdx.x * 256 + threadIdx.x;     // 0..6143
    int l = gid >> 11;
    int r = gid & 2047;
    int j = r >> 4, g = r & 15;
    const float* Wf = Wfij + l * 4096;
    const float* Wn = Wni + l * 4096;
    short8 out;
    #pragma unroll
    for (int i = 0; i < 8; i++) {
        int k = (g & 7) * 8 + i;
        float wv = (k < 32) ? Wf[k * 128 + j] : Wn[(k - 32) * 128 + j];
        short h = bf16_rne(wv);
        if (g >= 8) {
            float lo = wv - bf16_to_f32(h);
            out[i] = bf16_rne(lo);
        } else {
            out[i] = h;
        }
    }
    ((short8*)Wp)[(size_t)l * 2048 + j * 16 + (g ^ (j & 15))] = out;
}

// ---------------------------------------------------------------------------
// MFMA edge kernel, 256 threads / 4 waves / 128 edges per block.
// C[e][j] = bias[j] + sum_k A[e][k] W[k][j], A = [ef | nf[src]] via
// split-bf16 (ah*wh + al*wh + ah*wl). Wave w owns edges w*32..w*32+31.
// Epilogue: 4 wave-private chunks of 32 edges restaged through a 32x140
// region of sBuf; 8 threads/edge consume; logits staged in the dead tail
// of the W' region ([4480,4992) floats); block-linear output copies.
// LDS: exactly 32768 B -> 5 blocks/CU = 20 waves/CU.
// ---------------------------------------------------------------------------
template <bool WRITE_EF, bool GATHER_EF>
__global__ __launch_bounds__(256, 4) void edge_mfma(
    const float* __restrict__ ef_in,     // E x 32
    const int* __restrict__ eidx,        // permuted -> orig (GATHER_EF only)
    const int* __restrict__ src_p, const int* __restrict__ dst_p,
    const float* __restrict__ nf_cur,    // N x 32
    const float* __restrict__ f_nj,      // N x 128
    const short* __restrict__ Wp,        // layer slice: 2048 pre-swizzled granules
    const float* __restrict__ attn,      // 4x32 layer slice
    const float* __restrict__ bias,      // 128 layer slice
    float* __restrict__ logits,          // E x 4 (permuted order)
    float* __restrict__ ef_out) {        // E x 32 (permuted order)
    __shared__ float sBuf[8192];         // W' (32KB); epilogue: restage 32x140 + logits @4480

    int t = threadIdx.x;
    int lane = t & 63;
    int w = t >> 6;
    int m16 = lane & 15, ks = lane >> 4;
    int e0b = blockIdx.x * EB;

    // ---- stage W' (coalesced, already swizzled) ----
    {
        const float4* wp4 = (const float4*)Wp;
        float4* sw4 = (float4*)sBuf;
        #pragma unroll
        for (int i = 0; i < 8; i++) sw4[t + i * 256] = wp4[t + i * 256];
    }

    // ---- build A fragments from global (no LDS) ----
    short8 aefh[2], aefl[2], anfh[2], anfl[2];
    int eb = e0b + w * 32;
    #pragma unroll
    for (int mt = 0; mt < 2; mt++) {
        int ep = eb + mt * 16 + m16;
        long er = GATHER_EF ? (long)eidx[ep] : (long)ep;
        const float* efp = ef_in + (size_t)er * 32 + ks * 8;
        float4 a0 = *(const float4*)efp;
        float4 a1 = *(const float4*)(efp + 4);
        int sr = src_p[ep];
        const float* nfp = nf_cur + (size_t)sr * 32 + ks * 8;
        float4 b0 = *(const float4*)nfp;
        float4 b1 = *(const float4*)(nfp + 4);
        split8(a0, a1, aefh[mt], aefl[mt]);
        split8(b0, b1, anfh[mt], anfl[mt]);
    }
    __syncthreads();

    // ---- acc init = bias[j] (uniform down columns) ----
    f32x4 acc[2][8];
    #pragma unroll
    for (int jt = 0; jt < 8; jt++) {
        float bv = bias[jt * 16 + m16];
        #pragma unroll
        for (int mt = 0; mt < 2; mt++) {
            f32x4 c = {bv, bv, bv, bv};
            acc[mt][jt] = c;
        }
    }

    // ---- MFMA main loop ----
    const short8* sw8 = (const short8*)sBuf;
    #pragma unroll
    for (int jt = 0; jt < 8; jt++) {
        int jrow = (jt * 16 + m16) * 16;
        short8 bh0 = sw8[jrow + ((0 + ks) ^ m16)];    // wh, k 0:32  (ef)
        short8 bh1 = sw8[jrow + ((4 + ks) ^ m16)];    // wh, k 32:64 (nf)
        short8 bl0 = sw8[jrow + ((8 + ks) ^ m16)];    // wl, k 0:32
        short8 bl1 = sw8[jrow + ((12 + ks) ^ m16)];   // wl, k 32:64
        #pragma unroll
        for (int mt = 0; mt < 2; mt++) {
            f32x4 c = acc[mt][jt];
            c = __builtin_amdgcn_mfma_f32_16x16x32_bf16(aefh[mt], bh0, c, 0, 0, 0);
            c = __builtin_amdgcn_mfma_f32_16x16x32_bf16(anfh[mt], bh1, c, 0, 0, 0);
            c = __builtin_amdgcn_mfma_f32_16x16x32_bf16(aefl[mt], bh0, c, 0, 0, 0);
            c = __builtin_amdgcn_mfma_f32_16x16x32_bf16(anfl[mt], bh1, c, 0, 0, 0);
            c = __builtin_amdgcn_mfma_f32_16x16x32_bf16(aefh[mt], bl0, c, 0, 0, 0);
            c = __builtin_amdgcn_mfma_f32_16x16x32_bf16(anfh[mt], bl1, c, 0, 0, 0);
            acc[mt][jt] = c;
        }
    }

    // ---- epilogue: 4 wave-private chunks of 32 edges ----
    int sub = t & 7;              // 8 threads per edge
    int hh = sub >> 1;            // head 0..3
    int half = sub & 1;           // 16-col half of the head
    int e_l = t >> 3;             // edge 0..31 within chunk
    for (int ch = 0; ch < 4; ch++) {
        __syncthreads();   // W' reads / previous chunk copy complete
        if (w == ch) {
            #pragma unroll
            for (int mt = 0; mt < 2; mt++)
                #pragma unroll
                for (int jt = 0; jt < 8; jt++) {
                    int colp = (jt >> 1) * 36 + (jt & 1) * 16 + m16;
                    f32x4 c = acc[mt][jt];
                    #pragma unroll
                    for (int r = 0; r < 4; r++)
                        sBuf[(ks * 4 + mt * 16 + r) * 140 + colp] = c[r];
                }
        }
        __syncthreads();
        int ep = e0b + ch * 32 + e_l;
        const float* cr = sBuf + e_l * 140 + hh * 36 + half * 16;
        int dn = dst_p[ep];
        const float* fr = f_nj + (size_t)dn * 128 + hh * 32 + half * 16;
        const float* ar = attn + hh * 32 + half * 16;
        float x[16];
        float lg = 0.f;
        #pragma unroll
        for (int qq = 0; qq < 4; qq++) {
            float4 cv = *(const float4*)(cr + qq * 4);
            float4 fv = *(const float4*)(fr + qq * 4);
            float4 av = *(const float4*)(ar + qq * 4);
            float v0 = cv.x + fv.x; v0 = (v0 >= 0.f) ? v0 : 0.2f * v0; lg = fmaf(v0, av.x, lg);
            float v1 = cv.y + fv.y; v1 = (v1 >= 0.f) ? v1 : 0.2f * v1; lg = fmaf(v1, av.y, lg);
            float v2 = cv.z + fv.z; v2 = (v2 >= 0.f) ? v2 : 0.2f * v2; lg = fmaf(v2, av.z, lg);
            float v3 = cv.w + fv.w; v3 = (v3 >= 0.f) ? v3 : 0.2f * v3; lg = fmaf(v3, av.w, lg);
            x[qq * 4 + 0] = v0; x[qq * 4 + 1] = v1; x[qq * 4 + 2] = v2; x[qq * 4 + 3] = v3;
        }
        lg += __shfl_xor(lg, 1);            // combine the two halves of this head
        if (half == 0) sBuf[4480 + ch * 128 + e_l * 4 + hh] = lg;
        if (WRITE_EF) {
            #pragma unroll
            for (int i = 0; i < 16; i++) {
                x[i] += __shfl_xor(x[i], 2);    // head ^ 1
                x[i] += __shfl_xor(x[i], 4);    // head ^ 2
            }
            if (hh == 0) {
                // overwrite this edge's own (consumed) C columns half*16..+15
                float* mp = sBuf + e_l * 140 + half * 16;
                #pragma unroll
                for (int qq = 0; qq < 4; qq++)
                    *(float4*)(mp + qq * 4) = make_float4(x[qq*4] * 0.25f, x[qq*4+1] * 0.25f,
                                                          x[qq*4+2] * 0.25f, x[qq*4+3] * 0.25f);
            }
        }
        __syncthreads();
        if (WRITE_EF) {
            // block-linear copy: 32 rows x 32 floats -> efA contiguous (256 float4)
            float4* eo = (float4*)(ef_out + (size_t)(e0b + ch * 32) * 32);
            int row = t >> 3, qq = t & 7;
            eo[t] = *(const float4*)(sBuf + row * 140 + qq * 4);
        }
    }
    __syncthreads();
    if (t < 128)
        ((float4*)(logits + (size_t)e0b * 4))[t] = ((const float4*)(sBuf + 4480))[t];
}

// ---------------------------------------------------------------------------
// One wave per dst node; single pass (softmax is shift-invariant; logits are
// O(10) so raw exp is safe in fp32).
__global__ __launch_bounds__(256) void aggregate(
    const int* __restrict__ ro, const int* __restrict__ src_p,
    const float* __restrict__ logits,  // E x 4 (permuted)
    const float* __restrict__ nf_cur,  // N x 32
    float* __restrict__ agg) {         // N x 128
    int wid = (blockIdx.x * 256 + threadIdx.x) >> 6;
    int lane = threadIdx.x & 63;
    if (wid >= NNODE) return;
    int beg = ro[wid], end = ro[wid + 1];
    float* arow = agg + (size_t)wid * 128;
    if (beg == end) {
        arow[lane] = 0.f;
        arow[lane + 64] = 0.f;
        return;
    }
    int hA = lane >> 5;
    int k = lane & 31;
    float den1 = 0.f, den2 = 0.f, acc1 = 0.f, acc2 = 0.f;
    for (int i = beg; i < end; i++) {
        int s = src_p[i];
        float a1 = __expf(logits[(size_t)i * 4 + hA]);
        float a2 = __expf(logits[(size_t)i * 4 + hA + 2]);
        den1 += a1; den2 += a2;
        float v = nf_cur[(size_t)s * 32 + k];
        acc1 = fmaf(a1, v, acc1);
        acc2 = fmaf(a2, v, acc2);
    }
    arow[lane] = acc1 / den1;
    arow[lane + 64] = acc2 / den2;
}

// ---------------------------------------------------------------------------
// Tiled node-post GEMM (unchanged): 128-node tile, 256 thr, grid 782.
// ---------------------------------------------------------------------------
template <bool AGG, bool WRITE_FNJ>
__global__ __launch_bounds__(256, 3) void post_gemm(
    const float* __restrict__ Xin,
    const float* __restrict__ Wnode,
    const float* __restrict__ Wnj_n,
    float* __restrict__ nf_next,
    float* __restrict__ fnj_next) {
    __shared__ float sW1[128 * 34];
    __shared__ float sA[32 * 129];
    __shared__ float sW2[32 * 132];
    int t = threadIdx.x;
    int gn0 = blockIdx.x * 128;

    if (AGG) {
        const float4* wsrc = (const float4*)Wnode;
        #pragma unroll
        for (int i = 0; i < 4; i++) {
            int f = t + i * 256;
            int k = f >> 3, dq = f & 7;
            *(float4*)(sW1 + k * 34 + dq * 4) = wsrc[(k & 31) * 32 + (k >> 5) * 8 + dq];
        }
    }
    if (WRITE_FNJ) {
        const float4* wsrc = (const float4*)Wnj_n;
        #pragma unroll
        for (int i = 0; i < 4; i++) {
            int f = t + i * 256;
            int d = f >> 5, jq = f & 31;
            *(float4*)(sW2 + d * 132 + jq * 4) = wsrc[f];
        }
    }

    int nrow = t & 127;
    int half = t >> 7;
    bool rvalid = (gn0 + nrow) < NNODE;

    float c1[8][2];
    int cg = t & 15, ng = t >> 4;
    int c0 = cg * 2, n0 = ng * 8;

    if (AGG) {
        #pragma unroll
        for (int i = 0; i < 8; i++) { c1[i][0] = 0.f; c1[i][1] = 0.f; }
        const float4* arow = (const float4*)(Xin + (size_t)(gn0 + nrow) * 128);
        for (int ch = 0; ch < 4; ch++) {
            __syncthreads();
            #pragma unroll
            for (int q = 0; q < 4; q++) {
                float4 v = rvalid ? arow[ch * 8 + half * 4 + q]
                                  : make_float4(0.f, 0.f, 0.f, 0.f);
                int kk = half * 16 + q * 4;
                sA[(kk + 0) * 129 + nrow] = v.x;
                sA[(kk + 1) * 129 + nrow] = v.y;
                sA[(kk + 2) * 129 + nrow] = v.z;
                sA[(kk + 3) * 129 + nrow] = v.w;
            }
            __syncthreads();
            #pragma unroll 4
            for (int k = 0; k < 32; k++) {
                float4 a0 = *(const float4*)(sA + k * 129 + n0);
                float4 a1 = *(const float4*)(sA + k * 129 + n0 + 4);
                float2 wv = *(const float2*)(sW1 + (ch * 32 + k) * 34 + c0);
                float av[8] = {a0.x, a0.y, a0.z, a0.w, a1.x, a1.y, a1.z, a1.w};
                #pragma unroll
                for (int i = 0; i < 8; i++) {
                    c1[i][0] = fmaf(av[i], wv.x, c1[i][0]);
                    c1[i][1] = fmaf(av[i], wv.y, c1[i][1]);
                }
            }
        }
        #pragma unroll
        for (int i = 0; i < 8; i++) { c1[i][0] *= 0.25f; c1[i][1] *= 0.25f; }
        #pragma unroll
        for (int i = 0; i < 8; i++) {
            int n = gn0 + n0 + i;
            if (n < NNODE)
                *(float2*)(nf_next + (size_t)n * 32 + c0) = make_float2(c1[i][0], c1[i][1]);
        }
    }

    if (WRITE_FNJ) {
        __syncthreads();
        if (AGG) {
            #pragma unroll
            for (int i = 0; i < 8; i++) {
                sA[(c0 + 0) * 129 + n0 + i] = c1[i][0];
                sA[(c0 + 1) * 129 + n0 + i] = c1[i][1];
            }
        } else {
            const float4* xr = (const float4*)(Xin + (size_t)(gn0 + nrow) * 32);
            #pragma unroll
            for (int q = 0; q < 4; q++) {
                float4 v = rvalid ? xr[half * 4 + q] : make_float4(0.f, 0.f, 0.f, 0.f);
                int dd = half * 16 + q * 4;
                sA[(dd + 0) * 129 + nrow] = v.x;
                sA[(dd + 1) * 129 + nrow] = v.y;
                sA[(dd + 2) * 129 + nrow] = v.z;
                sA[(dd + 3) * 129 + nrow] = v.w;
            }
        }
        __syncthreads();

        int jg = t & 15, ng2 = t >> 4;
        int j0 = jg * 8, m0 = ng2 * 8;
        float f[8][8];
        #pragma unroll
        for (int i = 0; i < 8; i++)
            #pragma unroll
            for (int j = 0; j < 8; j++) f[i][j] = 0.f;
        #pragma unroll 4
        for (int d = 0; d < 32; d++) {
            float4 a0 = *(const float4*)(sA + d * 129 + m0);
            float4 a1 = *(const float4*)(sA + d * 129 + m0 + 4);
            float4 w0 = *(const float4*)(sW2 + d * 132 + j0);
            float4 w1 = *(const float4*)(sW2 + d * 132 + j0 + 4);
            float av[8] = {a0.x, a0.y, a0.z, a0.w, a1.x, a1.y, a1.z, a1.w};
            float wv[8] = {w0.x, w0.y, w0.z, w0.w, w1.x, w1.y, w1.z, w1.w};
            #pragma unroll
            for (int i = 0; i < 8; i++)
                #pragma unroll
                for (int j = 0; j < 8; j++)
                    f[i][j] = fmaf(av[i], wv[j], f[i][j]);
        }
        #pragma unroll
        for (int i = 0; i < 8; i++) {
            int n = gn0 + m0 + i;
            if (n < NNODE) {
                float* fo = fnj_next + (size_t)n * 128 + j0;
                *(float4*)(fo) = make_float4(f[i][0], f[i][1], f[i][2], f[i][3]);
                *(float4*)(fo + 4) = make_float4(f[i][4], f[i][5], f[i][6], f[i][7]);
            }
        }
    }
}

// ---------------------------------------------------------------------------
extern "C" void kernel_launch(void* const* d_in, const int* in_sizes, int n_in,
                              void* d_out, int out_size, void* d_ws, size_t ws_size,
                              hipStream_t stream) {
    const float* nf   = (const float*)d_in[0];
    const float* ef   = (const float*)d_in[1];
    const int*   src  = (const int*)d_in[2];
    const int*   dst  = (const int*)d_in[3];
    const float* Wni  = (const float*)d_in[4];
    const float* Wnj  = (const float*)d_in[5];
    const float* Wfij = (const float*)d_in[6];
    const float* Wnd  = (const float*)d_in[7];
    const float* attn = (const float*)d_in[8];
    const float* bias = (const float*)d_in[9];
    float* out = (float*)d_out;

    char* ws = (char*)d_ws;
    size_t off = 0;
    auto alloc = [&](size_t bytes) {
        void* p = ws + off;
        off += (bytes + 255) & ~(size_t)255;
        return p;
    };
    float* fnj    = (float*)alloc((size_t)NNODE * 128 * 4);
    float* agg    = (float*)alloc((size_t)(NNODE + 128) * 128 * 4);
    float* efA    = (float*)alloc((size_t)NEDGE * 32 * 4);
    float* logits = (float*)alloc((size_t)NEDGE * 4 * 4);
    float* nfA    = (float*)alloc((size_t)NNODE * 32 * 4);
    float* nfB    = (float*)alloc((size_t)NNODE * 32 * 4);
    short* Wp     = (short*)alloc((size_t)3 * 2048 * 16);   // split/transposed/swizzled W
    int*   counts = (int*)alloc((size_t)NNODE * 4);
    int*   cursor = (int*)alloc((size_t)NNODE * 4);
    int*   ro     = (int*)alloc((size_t)(NNODE + 1) * 4);
    int*   eidx   = (int*)alloc((size_t)NEDGE * 4);
    int*   src_p  = (int*)alloc((size_t)NEDGE * 4);
    int*   dst_p  = (int*)alloc((size_t)NEDGE * 4);
    int*   bsums  = (int*)alloc(1024 * 4);

    const int NB_E = (NEDGE + 255) / 256;          // 3125
    const int NB_N = (NNODE + 255) / 256;          // 391
    const int NB_AGG = (NNODE + 3) / 4;            // 25000
    const int NB_SCAN = (NNODE + 1023) / 1024;     // 98
    const int NB_ET = NEDGE / EB;                  // 6250
    const int NB_PG = (NNODE + 127) / 128;         // 782

    zero_ints<<<NB_N, 256, 0, stream>>>(counts, cursor, NNODE);
    count_dst<<<NB_E, 256, 0, stream>>>(dst, counts);
    scan_chunks<<<NB_SCAN, 256, 0, stream>>>(counts, ro, bsums, NNODE);
    scan_bsums<<<1, 256, 0, stream>>>(bsums, NB_SCAN);
    scan_add<<<NB_N, 256, 0, stream>>>(ro, bsums, NNODE);
    scatter_edges<<<NB_E, 256, 0, stream>>>(src, dst, ro, cursor, eidx, src_p, dst_p);
    wprep<<<24, 256, 0, stream>>>(Wfij, Wni, Wp);

    // layer-0 f_nj = nf @ Wnj[0]  (DIRECT path: GEMM2 only)
    post_gemm<false, true><<<NB_PG, 256, 0, stream>>>(nf, nullptr, Wnj, nullptr, fnj);

    // ----- layer 0 -----
    edge_mfma<true, true><<<NB_ET, 256, 0, stream>>>(ef, eidx, src_p, dst_p, nf, fnj,
                                                     Wp, attn, bias, logits, efA);
    aggregate<<<NB_AGG, 256, 0, stream>>>(ro, src_p, logits, nf, agg);
    post_gemm<true, true><<<NB_PG, 256, 0, stream>>>(agg, Wnd, Wnj + 4096, nfA, fnj);

    // ----- layer 1 -----
    edge_mfma<true, false><<<NB_ET, 256, 0, stream>>>(efA, nullptr, src_p, dst_p, nfA, fnj,
                                                      Wp + 16384, attn + 128, bias + 128,
                                                      logits, efA);
    aggregate<<<NB_AGG, 256, 0, stream>>>(ro, src_p, logits, nfA, agg);
    post_gemm<true, true><<<NB_PG, 256, 0, stream>>>(agg, Wnd + 4096, Wnj + 8192, nfB, fnj);

    // ----- layer 2 -----
    edge_mfma<false, false><<<NB_ET, 256, 0, stream>>>(efA, nullptr, src_p, dst_p, nfB, fnj,
                                                       Wp + 32768, attn + 256, bias + 256,
                                                       logits, nullptr);
    aggregate<<<NB_AGG, 256, 0, stream>>>(ro, src_p, logits, nfB, agg);
    post_gemm<true, false><<<NB_PG, 256, 0, stream>>>(agg, Wnd + 8192, nullptr, out, nullptr);
}

// Round 16
// 789.371 us; speedup vs baseline: 2.1847x; 1.1125x over previous
//
#include <hip/hip_runtime.h>

#define NNODE 100000
#define NEDGE 800000
#define EB 128
// H = 4, D = 32, H*D = 128, DN = DE = 32, NL = 3

typedef __attribute__((ext_vector_type(8))) short short8;   // 8 bf16 (4 VGPRs)
typedef __attribute__((ext_vector_type(4))) float f32x4;

__device__ __forceinline__ short bf16_rne(float f) {
    unsigned u = __float_as_uint(f);
    unsigned r = u + 0x7FFFu + ((u >> 16) & 1u);
    return (short)(r >> 16);
}
__device__ __forceinline__ float bf16_to_f32(short s) {
    return __uint_as_float(((unsigned)(unsigned short)s) << 16);
}
__device__ __forceinline__ void split8(float4 a, float4 b, short8& hi, short8& lo) {
    float v[8] = {a.x, a.y, a.z, a.w, b.x, b.y, b.z, b.w};
    #pragma unroll
    for (int i = 0; i < 8; i++) {
        short h = bf16_rne(v[i]);
        hi[i] = h;
        lo[i] = bf16_rne(v[i] - bf16_to_f32(h));
    }
}

// ---------------------------------------------------------------------------
// CSR build kernels (dst-indexed), run once per call
// ---------------------------------------------------------------------------
__global__ __launch_bounds__(256) void zero_ints(int* __restrict__ a, int* __restrict__ b, int n) {
    int i = blockIdx.x * 256 + threadIdx.x;
    if (i < n) { a[i] = 0; b[i] = 0; }
}

__global__ __launch_bounds__(256) void count_dst(const int* __restrict__ dst, int* __restrict__ counts) {
    int e = blockIdx.x * 256 + threadIdx.x;
    if (e < NEDGE) atomicAdd(&counts[dst[e]], 1);
}

__global__ __launch_bounds__(256) void scan_chunks(const int* __restrict__ counts, int* __restrict__ ro,
                                                   int* __restrict__ bsums, int n) {
    __shared__ int sh[256];
    int base = blockIdx.x * 1024;
    int t = threadIdx.x;
    int v[4];
    int s = 0;
    #pragma unroll
    for (int i = 0; i < 4; i++) {
        int idx = base + t * 4 + i;
        int c = (idx < n) ? counts[idx] : 0;
        v[i] = s; s += c;
    }
    sh[t] = s; __syncthreads();
    for (int off = 1; off < 256; off <<= 1) {
        int x = 0;
        if (t >= off) x = sh[t - off];
        __syncthreads();
        if (t >= off) sh[t] += x;
        __syncthreads();
    }
    int thr_excl = (t > 0) ? sh[t - 1] : 0;
    #pragma unroll
    for (int i = 0; i < 4; i++) {
        int idx = base + t * 4 + i;
        if (idx < n) ro[idx] = thr_excl + v[i];
    }
    if (t == 255) bsums[blockIdx.x] = sh[255];
}

__global__ __launch_bounds__(256) void scan_bsums(int* __restrict__ bsums, int nb) {
    __shared__ int sh[256];
    int t = threadIdx.x;
    int val = (t < nb) ? bsums[t] : 0;
    sh[t] = val; __syncthreads();
    for (int off = 1; off < 256; off <<= 1) {
        int x = 0;
        if (t >= off) x = sh[t - off];
        __syncthreads();
        if (t >= off) sh[t] += x;
        __syncthreads();
    }
    int excl = (t > 0) ? sh[t - 1] : 0;
    if (t < nb) bsums[t] = excl;
}

__global__ __launch_bounds__(256) void scan_add(int* __restrict__ ro, const int* __restrict__ bsums, int n) {
    int i = blockIdx.x * 256 + threadIdx.x;
    if (i < n) ro[i] += bsums[i >> 10];
    if (i == 0) ro[n] = NEDGE;
}

__global__ __launch_bounds__(256) void scatter_edges(const int* __restrict__ src, const int* __restrict__ dst,
                                                     const int* __restrict__ ro, int* __restrict__ cursor,
                                                     int* __restrict__ eidx, int* __restrict__ src_p,
                                                     int* __restrict__ dst_p) {
    int e = blockIdx.x * 256 + threadIdx.x;
    if (e < NEDGE) {
        int d = dst[e];
        int pos = atomicAdd(&cursor[d], 1);
        int idx = ro[d] + pos;
        eidx[idx] = e;
        src_p[idx] = src[e];
        dst_p[idx] = d;
    }
}

// ---------------------------------------------------------------------------
// W prep: per layer build W'[k 0:128][j 0:128] bf16, k<64 = hi of [Wfij;Wni],
// k>=64 = lo. Stored TRANSPOSED as granules: granule (j, g) = 8 bf16 of
// W'[g*8..g*8+7][j], placed at slot j*16 + (g ^ (j&15))  (XOR swizzle).
// ---------------------------------------------------------------------------
__global__ __launch_bounds__(256) void wprep(
    const float* __restrict__ Wfij, const float* __restrict__ Wni,
    short* __restrict__ Wp) {
    int gid = blockIdx.x * 256 + threadIdx.x;     // 0..6143
    int l = gid >> 11;
    int r = gid & 2047;
    int j = r >> 4, g = r & 15;
    const float* Wf = Wfij + l * 4096;
    const float* Wn = Wni + l * 4096;
    short8 out;
    #pragma unroll
    for (int i = 0; i < 8; i++) {
        int k = (g & 7) * 8 + i;
        float wv = (k < 32) ? Wf[k * 128 + j] : Wn[(k - 32) * 128 + j];
        short h = bf16_rne(wv);
        if (g >= 8) {
            float lo = wv - bf16_to_f32(h);
            out[i] = bf16_rne(lo);
        } else {
            out[i] = h;
        }
    }
    ((short8*)Wp)[(size_t)l * 2048 + j * 16 + (g ^ (j & 15))] = out;
}

// ---------------------------------------------------------------------------
// MFMA edge kernel (unchanged from R15), 256 threads / 128 edges per block.
// LDS: exactly 32768 B.
// ---------------------------------------------------------------------------
template <bool WRITE_EF, bool GATHER_EF>
__global__ __launch_bounds__(256, 4) void edge_mfma(
    const float* __restrict__ ef_in,     // E x 32
    const int* __restrict__ eidx,        // permuted -> orig (GATHER_EF only)
    const int* __restrict__ src_p, const int* __restrict__ dst_p,
    const float* __restrict__ nf_cur,    // N x 32
    const float* __restrict__ f_nj,      // N x 128
    const short* __restrict__ Wp,        // layer slice: 2048 pre-swizzled granules
    const float* __restrict__ attn,      // 4x32 layer slice
    const float* __restrict__ bias,      // 128 layer slice
    float* __restrict__ logits,          // E x 4 (permuted order)
    float* __restrict__ ef_out) {        // E x 32 (permuted order)
    __shared__ float sBuf[8192];         // W' (32KB); epilogue: restage 32x140 + logits @4480

    int t = threadIdx.x;
    int lane = t & 63;
    int w = t >> 6;
    int m16 = lane & 15, ks = lane >> 4;
    int e0b = blockIdx.x * EB;

    // ---- stage W' (coalesced, already swizzled) ----
    {
        const float4* wp4 = (const float4*)Wp;
        float4* sw4 = (float4*)sBuf;
        #pragma unroll
        for (int i = 0; i < 8; i++) sw4[t + i * 256] = wp4[t + i * 256];
    }

    // ---- build A fragments from global (no LDS) ----
    short8 aefh[2], aefl[2], anfh[2], anfl[2];
    int eb = e0b + w * 32;
    #pragma unroll
    for (int mt = 0; mt < 2; mt++) {
        int ep = eb + mt * 16 + m16;
        long er = GATHER_EF ? (long)eidx[ep] : (long)ep;
        const float* efp = ef_in + (size_t)er * 32 + ks * 8;
        float4 a0 = *(const float4*)efp;
        float4 a1 = *(const float4*)(efp + 4);
        int sr = src_p[ep];
        const float* nfp = nf_cur + (size_t)sr * 32 + ks * 8;
        float4 b0 = *(const float4*)nfp;
        float4 b1 = *(const float4*)(nfp + 4);
        split8(a0, a1, aefh[mt], aefl[mt]);
        split8(b0, b1, anfh[mt], anfl[mt]);
    }
    __syncthreads();

    // ---- acc init = bias[j] (uniform down columns) ----
    f32x4 acc[2][8];
    #pragma unroll
    for (int jt = 0; jt < 8; jt++) {
        float bv = bias[jt * 16 + m16];
        #pragma unroll
        for (int mt = 0; mt < 2; mt++) {
            f32x4 c = {bv, bv, bv, bv};
            acc[mt][jt] = c;
        }
    }

    // ---- MFMA main loop ----
    const short8* sw8 = (const short8*)sBuf;
    #pragma unroll
    for (int jt = 0; jt < 8; jt++) {
        int jrow = (jt * 16 + m16) * 16;
        short8 bh0 = sw8[jrow + ((0 + ks) ^ m16)];    // wh, k 0:32  (ef)
        short8 bh1 = sw8[jrow + ((4 + ks) ^ m16)];    // wh, k 32:64 (nf)
        short8 bl0 = sw8[jrow + ((8 + ks) ^ m16)];    // wl, k 0:32
        short8 bl1 = sw8[jrow + ((12 + ks) ^ m16)];   // wl, k 32:64
        #pragma unroll
        for (int mt = 0; mt < 2; mt++) {
            f32x4 c = acc[mt][jt];
            c = __builtin_amdgcn_mfma_f32_16x16x32_bf16(aefh[mt], bh0, c, 0, 0, 0);
            c = __builtin_amdgcn_mfma_f32_16x16x32_bf16(anfh[mt], bh1, c, 0, 0, 0);
            c = __builtin_amdgcn_mfma_f32_16x16x32_bf16(aefl[mt], bh0, c, 0, 0, 0);
            c = __builtin_amdgcn_mfma_f32_16x16x32_bf16(anfl[mt], bh1, c, 0, 0, 0);
            c = __builtin_amdgcn_mfma_f32_16x16x32_bf16(aefh[mt], bl0, c, 0, 0, 0);
            c = __builtin_amdgcn_mfma_f32_16x16x32_bf16(anfh[mt], bl1, c, 0, 0, 0);
            acc[mt][jt] = c;
        }
    }

    // ---- epilogue: 4 wave-private chunks of 32 edges ----
    int sub = t & 7;              // 8 threads per edge
    int hh = sub >> 1;            // head 0..3
    int half = sub & 1;           // 16-col half of the head
    int e_l = t >> 3;             // edge 0..31 within chunk
    for (int ch = 0; ch < 4; ch++) {
        __syncthreads();   // W' reads / previous chunk copy complete
        if (w == ch) {
            #pragma unroll
            for (int mt = 0; mt < 2; mt++)
                #pragma unroll
                for (int jt = 0; jt < 8; jt++) {
                    int colp = (jt >> 1) * 36 + (jt & 1) * 16 + m16;
                    f32x4 c = acc[mt][jt];
                    #pragma unroll
                    for (int r = 0; r < 4; r++)
                        sBuf[(ks * 4 + mt * 16 + r) * 140 + colp] = c[r];
                }
        }
        __syncthreads();
        int ep = e0b + ch * 32 + e_l;
        const float* cr = sBuf + e_l * 140 + hh * 36 + half * 16;
        int dn = dst_p[ep];
        const float* fr = f_nj + (size_t)dn * 128 + hh * 32 + half * 16;
        const float* ar = attn + hh * 32 + half * 16;
        float x[16];
        float lg = 0.f;
        #pragma unroll
        for (int qq = 0; qq < 4; qq++) {
            float4 cv = *(const float4*)(cr + qq * 4);
            float4 fv = *(const float4*)(fr + qq * 4);
            float4 av = *(const float4*)(ar + qq * 4);
            float v0 = cv.x + fv.x; v0 = (v0 >= 0.f) ? v0 : 0.2f * v0; lg = fmaf(v0, av.x, lg);
            float v1 = cv.y + fv.y; v1 = (v1 >= 0.f) ? v1 : 0.2f * v1; lg = fmaf(v1, av.y, lg);
            float v2 = cv.z + fv.z; v2 = (v2 >= 0.f) ? v2 : 0.2f * v2; lg = fmaf(v2, av.z, lg);
            float v3 = cv.w + fv.w; v3 = (v3 >= 0.f) ? v3 : 0.2f * v3; lg = fmaf(v3, av.w, lg);
            x[qq * 4 + 0] = v0; x[qq * 4 + 1] = v1; x[qq * 4 + 2] = v2; x[qq * 4 + 3] = v3;
        }
        lg += __shfl_xor(lg, 1);            // combine the two halves of this head
        if (half == 0) sBuf[4480 + ch * 128 + e_l * 4 + hh] = lg;
        if (WRITE_EF) {
            #pragma unroll
            for (int i = 0; i < 16; i++) {
                x[i] += __shfl_xor(x[i], 2);    // head ^ 1
                x[i] += __shfl_xor(x[i], 4);    // head ^ 2
            }
            if (hh == 0) {
                // overwrite this edge's own (consumed) C columns half*16..+15
                float* mp = sBuf + e_l * 140 + half * 16;
                #pragma unroll
                for (int qq = 0; qq < 4; qq++)
                    *(float4*)(mp + qq * 4) = make_float4(x[qq*4] * 0.25f, x[qq*4+1] * 0.25f,
                                                          x[qq*4+2] * 0.25f, x[qq*4+3] * 0.25f);
            }
        }
        __syncthreads();
        if (WRITE_EF) {
            // block-linear copy: 32 rows x 32 floats -> efA contiguous (256 float4)
            float4* eo = (float4*)(ef_out + (size_t)(e0b + ch * 32) * 32);
            int row = t >> 3, qq = t & 7;
            eo[t] = *(const float4*)(sBuf + row * 140 + qq * 4);
        }
    }
    __syncthreads();
    if (t < 128)
        ((float4*)(logits + (size_t)e0b * 4))[t] = ((const float4*)(sBuf + 4480))[t];
}

// ---------------------------------------------------------------------------
// One wave per dst node; single pass; gather loop manually unrolled x4 so
// 4 independent src_p->nf dependent chains are in flight simultaneously.
__global__ __launch_bounds__(256) void aggregate(
    const int* __restrict__ ro, const int* __restrict__ src_p,
    const float* __restrict__ logits,  // E x 4 (permuted)
    const float* __restrict__ nf_cur,  // N x 32
    float* __restrict__ agg) {         // N x 128
    int wid = (blockIdx.x * 256 + threadIdx.x) >> 6;
    int lane = threadIdx.x & 63;
    if (wid >= NNODE) return;
    int beg = ro[wid], end = ro[wid + 1];
    float* arow = agg + (size_t)wid * 128;
    if (beg == end) {
        arow[lane] = 0.f;
        arow[lane + 64] = 0.f;
        return;
    }
    int hA = lane >> 5;
    int k = lane & 31;
    float den1 = 0.f, den2 = 0.f, acc1 = 0.f, acc2 = 0.f;
    int i = beg;
    for (; i + 4 <= end; i += 4) {
        int s0 = src_p[i], s1 = src_p[i + 1], s2 = src_p[i + 2], s3 = src_p[i + 3];
        float4 g0 = *(const float4*)(logits + (size_t)i * 4);
        float4 g1 = *(const float4*)(logits + (size_t)(i + 1) * 4);
        float4 g2 = *(const float4*)(logits + (size_t)(i + 2) * 4);
        float4 g3 = *(const float4*)(logits + (size_t)(i + 3) * 4);
        float v0 = nf_cur[(size_t)s0 * 32 + k];
        float v1 = nf_cur[(size_t)s1 * 32 + k];
        float v2 = nf_cur[(size_t)s2 * 32 + k];
        float v3 = nf_cur[(size_t)s3 * 32 + k];
        float a0 = __expf(hA ? g0.y : g0.x), b0 = __expf(hA ? g0.w : g0.z);
        float a1 = __expf(hA ? g1.y : g1.x), b1 = __expf(hA ? g1.w : g1.z);
        float a2 = __expf(hA ? g2.y : g2.x), b2 = __expf(hA ? g2.w : g2.z);
        float a3 = __expf(hA ? g3.y : g3.x), b3 = __expf(hA ? g3.w : g3.z);
        den1 += a0 + a1 + a2 + a3;
        den2 += b0 + b1 + b2 + b3;
        acc1 = fmaf(a0, v0, fmaf(a1, v1, fmaf(a2, v2, fmaf(a3, v3, acc1))));
        acc2 = fmaf(b0, v0, fmaf(b1, v1, fmaf(b2, v2, fmaf(b3, v3, acc2))));
    }
    for (; i < end; i++) {
        int s = src_p[i];
        float4 g = *(const float4*)(logits + (size_t)i * 4);
        float v = nf_cur[(size_t)s * 32 + k];
        float a = __expf(hA ? g.y : g.x);
        float b = __expf(hA ? g.w : g.z);
        den1 += a; den2 += b;
        acc1 = fmaf(a, v, acc1);
        acc2 = fmaf(b, v, acc2);
    }
    arow[lane] = acc1 / den1;
    arow[lane + 64] = acc2 / den2;
}

// ---------------------------------------------------------------------------
// Tiled node-post GEMM (unchanged): 128-node tile, 256 thr, grid 782.
// ---------------------------------------------------------------------------
template <bool AGG, bool WRITE_FNJ>
__global__ __launch_bounds__(256, 3) void post_gemm(
    const float* __restrict__ Xin,
    const float* __restrict__ Wnode,
    const float* __restrict__ Wnj_n,
    float* __restrict__ nf_next,
    float* __restrict__ fnj_next) {
    __shared__ float sW1[128 * 34];
    __shared__ float sA[32 * 129];
    __shared__ float sW2[32 * 132];
    int t = threadIdx.x;
    int gn0 = blockIdx.x * 128;

    if (AGG) {
        const float4* wsrc = (const float4*)Wnode;
        #pragma unroll
        for (int i = 0; i < 4; i++) {
            int f = t + i * 256;
            int k = f >> 3, dq = f & 7;
            *(float4*)(sW1 + k * 34 + dq * 4) = wsrc[(k & 31) * 32 + (k >> 5) * 8 + dq];
        }
    }
    if (WRITE_FNJ) {
        const float4* wsrc = (const float4*)Wnj_n;
        #pragma unroll
        for (int i = 0; i < 4; i++) {
            int f = t + i * 256;
            int d = f >> 5, jq = f & 31;
            *(float4*)(sW2 + d * 132 + jq * 4) = wsrc[f];
        }
    }

    int nrow = t & 127;
    int half = t >> 7;
    bool rvalid = (gn0 + nrow) < NNODE;

    float c1[8][2];
    int cg = t & 15, ng = t >> 4;
    int c0 = cg * 2, n0 = ng * 8;

    if (AGG) {
        #pragma unroll
        for (int i = 0; i < 8; i++) { c1[i][0] = 0.f; c1[i][1] = 0.f; }
        const float4* arow = (const float4*)(Xin + (size_t)(gn0 + nrow) * 128);
        for (int ch = 0; ch < 4; ch++) {
            __syncthreads();
            #pragma unroll
            for (int q = 0; q < 4; q++) {
                float4 v = rvalid ? arow[ch * 8 + half * 4 + q]
                                  : make_float4(0.f, 0.f, 0.f, 0.f);
                int kk = half * 16 + q * 4;
                sA[(kk + 0) * 129 + nrow] = v.x;
                sA[(kk + 1) * 129 + nrow] = v.y;
                sA[(kk + 2) * 129 + nrow] = v.z;
                sA[(kk + 3) * 129 + nrow] = v.w;
            }
            __syncthreads();
            #pragma unroll 4
            for (int k = 0; k < 32; k++) {
                float4 a0 = *(const float4*)(sA + k * 129 + n0);
                float4 a1 = *(const float4*)(sA + k * 129 + n0 + 4);
                float2 wv = *(const float2*)(sW1 + (ch * 32 + k) * 34 + c0);
                float av[8] = {a0.x, a0.y, a0.z, a0.w, a1.x, a1.y, a1.z, a1.w};
                #pragma unroll
                for (int i = 0; i < 8; i++) {
                    c1[i][0] = fmaf(av[i], wv.x, c1[i][0]);
                    c1[i][1] = fmaf(av[i], wv.y, c1[i][1]);
                }
            }
        }
        #pragma unroll
        for (int i = 0; i < 8; i++) { c1[i][0] *= 0.25f; c1[i][1] *= 0.25f; }
        #pragma unroll
        for (int i = 0; i < 8; i++) {
            int n = gn0 + n0 + i;
            if (n < NNODE)
                *(float2*)(nf_next + (size_t)n * 32 + c0) = make_float2(c1[i][0], c1[i][1]);
        }
    }

    if (WRITE_FNJ) {
        __syncthreads();
        if (AGG) {
            #pragma unroll
            for (int i = 0; i < 8; i++) {
                sA[(c0 + 0) * 129 + n0 + i] = c1[i][0];
                sA[(c0 + 1) * 129 + n0 + i] = c1[i][1];
            }
        } else {
            const float4* xr = (const float4*)(Xin + (size_t)(gn0 + nrow) * 32);
            #pragma unroll
            for (int q = 0; q < 4; q++) {
                float4 v = rvalid ? xr[half * 4 + q] : make_float4(0.f, 0.f, 0.f, 0.f);
                int dd = half * 16 + q * 4;
                sA[(dd + 0) * 129 + nrow] = v.x;
                sA[(dd + 1) * 129 + nrow] = v.y;
                sA[(dd + 2) * 129 + nrow] = v.z;
                sA[(dd + 3) * 129 + nrow] = v.w;
            }
        }
        __syncthreads();

        int jg = t & 15, ng2 = t >> 4;
        int j0 = jg * 8, m0 = ng2 * 8;
        float f[8][8];
        #pragma unroll
        for (int i = 0; i < 8; i++)
            #pragma unroll
            for (int j = 0; j < 8; j++) f[i][j] = 0.f;
        #pragma unroll 4
        for (int d = 0; d < 32; d++) {
            float4 a0 = *(const float4*)(sA + d * 129 + m0);
            float4 a1 = *(const float4*)(sA + d * 129 + m0 + 4);
            float4 w0 = *(const float4*)(sW2 + d * 132 + j0);
            float4 w1 = *(const float4*)(sW2 + d * 132 + j0 + 4);
            float av[8] = {a0.x, a0.y, a0.z, a0.w, a1.x, a1.y, a1.z, a1.w};
            float wv[8] = {w0.x, w0.y, w0.z, w0.w, w1.x, w1.y, w1.z, w1.w};
            #pragma unroll
            for (int i = 0; i < 8; i++)
                #pragma unroll
                for (int j = 0; j < 8; j++)
                    f[i][j] = fmaf(av[i], wv[j], f[i][j]);
        }
        #pragma unroll
        for (int i = 0; i < 8; i++) {
            int n = gn0 + m0 + i;
            if (n < NNODE) {
                float* fo = fnj_next + (size_t)n * 128 + j0;
                *(float4*)(fo) = make_float4(f[i][0], f[i][1], f[i][2], f[i][3]);
                *(float4*)(fo + 4) = make_float4(f[i][4], f[i][5], f[i][6], f[i][7]);
            }
        }
    }
}

// ---------------------------------------------------------------------------
extern "C" void kernel_launch(void* const* d_in, const int* in_sizes, int n_in,
                              void* d_out, int out_size, void* d_ws, size_t ws_size,
                              hipStream_t stream) {
    const float* nf   = (const float*)d_in[0];
    const float* ef   = (const float*)d_in[1];
    const int*   src  = (const int*)d_in[2];
    const int*   dst  = (const int*)d_in[3];
    const float* Wni  = (const float*)d_in[4];
    const float* Wnj  = (const float*)d_in[5];
    const float* Wfij = (const float*)d_in[6];
    const float* Wnd  = (const float*)d_in[7];
    const float* attn = (const float*)d_in[8];
    const float* bias = (const float*)d_in[9];
    float* out = (float*)d_out;

    char* ws = (char*)d_ws;
    size_t off = 0;
    auto alloc = [&](size_t bytes) {
        void* p = ws + off;
        off += (bytes + 255) & ~(size_t)255;
        return p;
    };
    float* fnj    = (float*)alloc((size_t)NNODE * 128 * 4);
    float* agg    = (float*)alloc((size_t)(NNODE + 128) * 128 * 4);
    float* efA    = (float*)alloc((size_t)NEDGE * 32 * 4);
    float* logits = (float*)alloc((size_t)NEDGE * 4 * 4);
    float* nfA    = (float*)alloc((size_t)NNODE * 32 * 4);
    float* nfB    = (float*)alloc((size_t)NNODE * 32 * 4);
    short* Wp     = (short*)alloc((size_t)3 * 2048 * 16);   // split/transposed/swizzled W
    int*   counts = (int*)alloc((size_t)NNODE * 4);
    int*   cursor = (int*)alloc((size_t)NNODE * 4);
    int*   ro     = (int*)alloc((size_t)(NNODE + 1) * 4);
    int*   eidx   = (int*)alloc((size_t)NEDGE * 4);
    int*   src_p  = (int*)alloc((size_t)NEDGE * 4);
    int*   dst_p  = (int*)alloc((size_t)NEDGE * 4);
    int*   bsums  = (int*)alloc(1024 * 4);

    const int NB_E = (NEDGE + 255) / 256;          // 3125
    const int NB_N = (NNODE + 255) / 256;          // 391
    const int NB_AGG = (NNODE + 3) / 4;            // 25000
    const int NB_SCAN = (NNODE + 1023) / 1024;     // 98
    const int NB_ET = NEDGE / EB;                  // 6250
    const int NB_PG = (NNODE + 127) / 128;         // 782

    zero_ints<<<NB_N, 256, 0, stream>>>(counts, cursor, NNODE);
    count_dst<<<NB_E, 256, 0, stream>>>(dst, counts);
    scan_chunks<<<NB_SCAN, 256, 0, stream>>>(counts, ro, bsums, NNODE);
    scan_bsums<<<1, 256, 0, stream>>>(bsums, NB_SCAN);
    scan_add<<<NB_N, 256, 0, stream>>>(ro, bsums, NNODE);
    scatter_edges<<<NB_E, 256, 0, stream>>>(src, dst, ro, cursor, eidx, src_p, dst_p);
    wprep<<<24, 256, 0, stream>>>(Wfij, Wni, Wp);

    // layer-0 f_nj = nf @ Wnj[0]  (DIRECT path: GEMM2 only)
    post_gemm<false, true><<<NB_PG, 256, 0, stream>>>(nf, nullptr, Wnj, nullptr, fnj);

    // ----- layer 0 -----
    edge_mfma<true, true><<<NB_ET, 256, 0, stream>>>(ef, eidx, src_p, dst_p, nf, fnj,
                                                     Wp, attn, bias, logits, efA);
    aggregate<<<NB_AGG, 256, 0, stream>>>(ro, src_p, logits, nf, agg);
    post_gemm<true, true><<<NB_PG, 256, 0, stream>>>(agg, Wnd, Wnj + 4096, nfA, fnj);

    // ----- layer 1 -----
    edge_mfma<true, false><<<NB_ET, 256, 0, stream>>>(efA, nullptr, src_p, dst_p, nfA, fnj,
                                                      Wp + 16384, attn + 128, bias + 128,
                                                      logits, efA);
    aggregate<<<NB_AGG, 256, 0, stream>>>(ro, src_p, logits, nfA, agg);
    post_gemm<true, true><<<NB_PG, 256, 0, stream>>>(agg, Wnd + 4096, Wnj + 8192, nfB, fnj);

    // ----- layer 2 -----
    edge_mfma<false, false><<<NB_ET, 256, 0, stream>>>(efA, nullptr, src_p, dst_p, nfB, fnj,
                                                       Wp + 32768, attn + 256, bias + 256,
                                                       logits, nullptr);
    aggregate<<<NB_AGG, 256, 0, stream>>>(ro, src_p, logits, nfB, agg);
    post_gemm<true, false><<<NB_PG, 256, 0, stream>>>(agg, Wnd + 8192, nullptr, out, nullptr);
}